// Round 6
// baseline (580.949 us; speedup 1.0000x reference)
//
#include <hip/hip_runtime.h>
#include <hip/hip_fp16.h>

#define N_NODES 100000
#define N_EDGES 1600000
#define BN_EPS 1e-5f
#define NBLK_E 6250      /* N_EDGES / 256 exact */
#define NBLK_G 3125      /* N_NODES / 32 exact */
#define NBLK_N 391       /* ceil(N_NODES/256) */
#define NBINS 391        /* buckets of 256 nodes */
#define BCAP 4608        /* entries per bucket (lambda=4096, +8 sigma) */
#define PT 4096          /* partition tile (edges per block) */
#define NPART 391        /* ceil(N_EDGES/PT) */
#define OVF_CAP 32768
#define A18 262144.0f
#define A18_INV 3.814697265625e-6f   /* 2^-18 */
typedef unsigned long long ull;
typedef unsigned int uint;

// bucket entry = local_d(8) | edge_idx(21) | src(17) | attr_q18(18)
// csr2 entry (after finalize) = attr_q18(high32) | src(low32)
// csr2 entry (after nrm blocks of gemm_l0_nrm) = f32(attr*dinv[src]) | src

// ---------------- init
__global__ void init_kernel(int* gcnt, int* win, uint* zbitmap, int* flags, float* bnacc) {
    int v = blockIdx.x * blockDim.x + threadIdx.x;
    if (v < N_NODES) win[v] = -1;
    if (v < NBINS) gcnt[v] = 0;
    if (v < 3125) zbitmap[v] = 0;
    if (v < 2) flags[v] = 0;          // [0]=zero-indeg-any  [1]=ovf_cnt
    if (v < 256) bnacc[v] = 0.0f;     // [2 layers][sum64|sq64]
}

// ---------------- partition (LDS-staged counting sort into 391 buckets) + fused h0 GEMM
__launch_bounds__(256)
__global__ void partition_gemm(const int* __restrict__ src, const int* __restrict__ dst,
                               const float* __restrict__ attr,
                               ull* __restrict__ bucket, int* __restrict__ gcnt,
                               int* __restrict__ flags, int* __restrict__ ovf_b,
                               ull* __restrict__ ovf_e,
                               const float* __restrict__ x, const float* __restrict__ lin_W,
                               const float* __restrict__ lin_b, float* __restrict__ h0) {
    __shared__ ull ent[PT];               // 32 KB
    __shared__ unsigned short ebin[PT];   // 8 KB
    __shared__ int hist[NBINS];
    __shared__ int cur[NBINS];
    __shared__ int gdel[NBINS];
    __shared__ int sc[512];
    int t = threadIdx.x;
    if (blockIdx.x < NPART) {
        int e0 = blockIdx.x * PT;
        int n = N_EDGES - e0; if (n > PT) n = PT;
        for (int b = t; b < NBINS; b += 256) hist[b] = 0;
        __syncthreads();
        for (int k = t; k < n; k += 256) atomicAdd(&hist[dst[e0 + k] >> 8], 1);
        __syncthreads();
        sc[t] = (t < NBINS) ? hist[t] : 0;
        sc[t + 256] = (t + 256 < NBINS) ? hist[t + 256] : 0;
        __syncthreads();
        for (int off = 1; off < 512; off <<= 1) {
            int a0 = sc[t] + ((t >= off) ? sc[t - off] : 0);
            int a1 = sc[t + 256] + sc[t + 256 - off];
            __syncthreads();
            sc[t] = a0; sc[t + 256] = a1;
            __syncthreads();
        }
        for (int b = t; b < NBINS; b += 256) {
            int lb = sc[b] - hist[b];
            cur[b] = lb;
            int gb = atomicAdd(&gcnt[b], hist[b]);
            gdel[b] = gb - lb;
        }
        __syncthreads();
        for (int k = t; k < n; k += 256) {
            int i = e0 + k;
            int d = dst[i];
            uint aq = (uint)(attr[i] * A18); if (aq > 0x3FFFFu) aq = 0x3FFFFu;
            int bin = d >> 8;
            ull e = ((ull)(d & 255) << 56) | ((ull)i << 35) | ((ull)src[i] << 18) | aq;
            int p = atomicAdd(&cur[bin], 1);
            ent[p] = e;
            ebin[p] = (unsigned short)bin;
        }
        __syncthreads();
        for (int k = t; k < n; k += 256) {
            int b = ebin[k];
            int off = k + gdel[b];
            if (off < BCAP) bucket[(size_t)b * BCAP + off] = ent[k];
            else {
                int q = atomicAdd(&flags[1], 1);
                if (q < OVF_CAP) { ovf_b[q] = b; ovf_e[q] = ent[k]; }
            }
        }
        return;
    }
    // ---- fused GEMM blocks: h0 = x @ lin_W + lin_b
    float* xs = (float*)ent;
    int lane = t & 63, w = t >> 6;
    int base = (blockIdx.x - NPART) * 32;
    const float4* Xv = (const float4*)(x + (size_t)base * 64);
    float4* xsv = (float4*)xs;
    xsv[t] = Xv[t];
    xsv[t + 256] = Xv[t + 256];
    float wc[64];
    #pragma unroll
    for (int k = 0; k < 64; ++k) wc[k] = lin_W[k * 64 + lane];
    __syncthreads();
    float bval = lin_b[lane];
    for (int rr = 0; rr < 8; ++rr) {
        int rl = w * 8 + rr;
        float acc = bval;
        #pragma unroll
        for (int k = 0; k < 64; ++k) acc = fmaf(xs[rl * 64 + k], wc[k], acc);
        h0[(size_t)(base + rl) * 64 + lane] = acc;
    }
}

// ---------------- finalize+reorder: node-sort entries -> csr2 (coalesced),
// per-node start/len, deg->dinv, last-write-winner attr, zero-indeg marks.
__launch_bounds__(256)
__global__ void finalize_reorder(const ull* __restrict__ bucket, const int* __restrict__ gcnt,
                                 const int* __restrict__ ovf_b, const ull* __restrict__ ovf_e,
                                 int* __restrict__ flags, uint* __restrict__ zbitmap,
                                 float* __restrict__ dinv, float* __restrict__ wa,
                                 ull* __restrict__ csr2, int* __restrict__ startv,
                                 int* __restrict__ lenv) {
    __shared__ ull ent[BCAP];        // 36.8 KB
    __shared__ int cnt[256];
    __shared__ int sc[256];
    __shared__ int cur[256];
    __shared__ int cbase[257];
    int t = threadIdx.x, b = blockIdx.x;
    int len = gcnt[b], blen = len < BCAP ? len : BCAP;
    const ull* bb = bucket + (size_t)b * BCAP;
    cnt[t] = 0;
    __syncthreads();
    ull r[18];
    #pragma unroll
    for (int k = 0; k < 18; ++k) {
        int j = k * 256 + t;
        r[k] = 0;
        if (j < blen) {
            ull e = bb[j];
            r[k] = e;
            atomicAdd(&cnt[(int)(e >> 56)], 1);
        }
    }
    __syncthreads();
    sc[t] = cnt[t];
    __syncthreads();
    for (int off = 1; off < 256; off <<= 1) {
        int a = sc[t] + ((t >= off) ? sc[t - off] : 0);
        __syncthreads();
        sc[t] = a;
        __syncthreads();
    }
    cbase[t + 1] = sc[t];
    if (t == 0) cbase[0] = 0;
    cur[t] = sc[t] - cnt[t];
    __syncthreads();
    #pragma unroll
    for (int k = 0; k < 18; ++k) {
        int j = k * 256 + t;
        if (j < blen) {
            ull e = r[k];
            int p = atomicAdd(&cur[(int)(e >> 56)], 1);
            ent[p] = e;
        }
    }
    __syncthreads();
    size_t base = (size_t)b * BCAP;
    for (int k = t; k < blen; k += 256) {
        ull e = ent[k];
        csr2[base + k] = (((ull)(e & 0x3FFFFull)) << 32) | ((e >> 18) & 0x1FFFFull);
    }
    int j0 = cbase[t], j1 = cbase[t + 1];
    float sum = 0.0f; uint winx = 0, wat = 0;
    for (int j = j0; j < j1; ++j) {
        ull e = ent[j];
        uint aq = (uint)(e & 0x3FFFFull);
        sum += (float)aq * A18_INV;
        uint ei = (uint)((e >> 35) & 0x1FFFFFull) + 1u;
        if (ei > winx) { winx = ei; wat = aq; }
    }
    if (len > BCAP) {                      // overflow (practically never)
        int oc = flags[1]; if (oc > OVF_CAP) oc = OVF_CAP;
        for (int q = 0; q < oc; ++q) {
            if (ovf_b[q] != b) continue;
            ull e = ovf_e[q];
            if ((int)(e >> 56) != t) continue;
            uint aq = (uint)(e & 0x3FFFFull);
            sum += (float)aq * A18_INV;
            uint ei = (uint)((e >> 35) & 0x1FFFFFull) + 1u;
            if (ei > winx) { winx = ei; wat = aq; }
        }
    }
    int v = b * 256 + t;
    if (v < N_NODES) {
        dinv[v] = rsqrtf(1.0f + sum);
        startv[v] = (int)(base + j0);
        lenv[v] = j1 - j0;
        if (winx > 0) {
            wa[v] = (float)wat * A18_INV;
        } else {
            wa[v] = -1.0f;
            atomicOr(&zbitmap[v >> 5], 1u << (v & 31));
            flags[0] = 1;
        }
    }
}

// ---------------- fixup: src-side winner for zero-in-degree nodes (early-exit)
__global__ void fixup_scan(const int* __restrict__ src, const int* __restrict__ flags,
                           const uint* __restrict__ zbitmap, int* __restrict__ win) {
    if (flags[0] == 0) return;
    int i = blockIdx.x * 256 + threadIdx.x;
    int s = src[i];
    if ((zbitmap[s >> 5] >> (s & 31)) & 1u) atomicMax(&win[s], i);
}

__global__ void fixup_apply(const int* __restrict__ flags, const uint* __restrict__ zbitmap,
                            const int* __restrict__ win, const float* __restrict__ attr,
                            float* __restrict__ wa) {
    if (flags[0] == 0) return;
    int v = blockIdx.x * 256 + threadIdx.x;
    if (v >= N_NODES) return;
    if (((zbitmap[v >> 5] >> (v & 31)) & 1u) && win[v] >= 0) wa[v] = attr[win[v]];
}

// ---------------- layer-0 GEMM + fused nrm-precompute blocks
// nrm blocks: csr2 entry (aq<<32|src) -> (f32(aq*dinv[src])<<32|src)
__launch_bounds__(256)
__global__ void gemm_l0_nrm(const float* __restrict__ h0, const float* __restrict__ W,
                            const float* __restrict__ wa, const float* __restrict__ ew,
                            const float* __restrict__ eb, __half* __restrict__ xw16,
                            ull* __restrict__ csr2, const int* __restrict__ gcnt,
                            const float* __restrict__ dinv) {
    __shared__ float xs[2048];
    int t = threadIdx.x;
    if (blockIdx.x < NBINS) {
        int b = blockIdx.x;
        int len = gcnt[b], blen = len < BCAP ? len : BCAP;
        ull* c = csr2 + (size_t)b * BCAP;
        for (int k = t; k < blen; k += 256) {
            ull pk = c[k];
            uint s = (uint)pk;
            float np = (float)(uint)(pk >> 32) * A18_INV * dinv[s];
            c[k] = ((ull)__float_as_uint(np) << 32) | s;
        }
        return;
    }
    int lane = t & 63, w = t >> 6;
    int base = (blockIdx.x - NBINS) * 32;
    const float4* Hv = (const float4*)(h0 + (size_t)base * 64);
    #pragma unroll
    for (int q = 0; q < 2; ++q) {
        int idx = t + q * 256;
        int rl = idx >> 4, f0 = (idx & 15) * 4;
        float4 v = Hv[idx];
        float wav = wa[base + rl];
        if (wav >= 0.0f) {
            v.x = fmaxf(fmaf(wav, ew[f0 + 0], v.x + eb[f0 + 0]), 0.0f);
            v.y = fmaxf(fmaf(wav, ew[f0 + 1], v.y + eb[f0 + 1]), 0.0f);
            v.z = fmaxf(fmaf(wav, ew[f0 + 2], v.z + eb[f0 + 2]), 0.0f);
            v.w = fmaxf(fmaf(wav, ew[f0 + 3], v.w + eb[f0 + 3]), 0.0f);
        }
        ((float4*)xs)[idx] = v;
    }
    float wc[64];
    #pragma unroll
    for (int k = 0; k < 64; ++k) wc[k] = W[k * 64 + lane];
    __syncthreads();
    for (int rr = 0; rr < 8; ++rr) {
        int rl = w * 8 + rr;
        float acc = 0.0f;
        #pragma unroll
        for (int k = 0; k < 64; ++k) acc = fmaf(xs[rl * 64 + k], wc[k], acc);
        xw16[(size_t)(base + rl) * 64 + lane] = __float2half(acc);
    }
}

// ---------------- layer-1 GEMM: stage agg0 + BN0 + relu, write out[:,0:64], fp16 xw
__launch_bounds__(256)
__global__ void gemm_l1(const float* __restrict__ agg, const float* __restrict__ bnacc,
                        const float* __restrict__ gamma, const float* __restrict__ beta,
                        const float* __restrict__ W, float* __restrict__ out,
                        __half* __restrict__ xw16) {
    __shared__ float xs[2048];
    int t = threadIdx.x, lane = t & 63, w = t >> 6;
    int base = blockIdx.x * 32;
    const float4* Av = (const float4*)(agg + (size_t)base * 64);
    const float invN = 1.0f / (float)N_NODES;
    #pragma unroll
    for (int q = 0; q < 2; ++q) {
        int idx = t + q * 256;
        int rl = idx >> 4, f0 = (idx & 15) * 4;
        float4 v = Av[idx];
        float vv[4] = {v.x, v.y, v.z, v.w};
        #pragma unroll
        for (int c = 0; c < 4; ++c) {
            int f = f0 + c;
            float mean = bnacc[f] * invN;
            float var = bnacc[64 + f] * invN - mean * mean;
            float scl = gamma[f] * rsqrtf(var + BN_EPS);
            float bs = beta[f] - mean * scl;
            vv[c] = fmaxf(fmaf(vv[c], scl, bs), 0.0f);
        }
        float4 r = {vv[0], vv[1], vv[2], vv[3]};
        ((float4*)xs)[idx] = r;
        *(float4*)(out + (size_t)(base + rl) * 128 + f0) = r;   // out[:, 0:64]
    }
    float wc[64];
    #pragma unroll
    for (int k = 0; k < 64; ++k) wc[k] = W[k * 64 + lane];
    __syncthreads();
    for (int rr = 0; rr < 8; ++rr) {
        int rl = w * 8 + rr;
        float acc = 0.0f;
        #pragma unroll
        for (int k = 0; k < 64; ++k) acc = fmaf(xs[rl * 64 + k], wc[k], acc);
        xw16[(size_t)(base + rl) * 64 + lane] = __float2half(acc);
    }
}

// ---------------- gather v2: wave-per-node; uniform broadcast entry loads (no shuffles);
// half-wave row-pair: lane = (feat-pair fl, row-parity half); 4-deep unroll = 8 rows in flight
__launch_bounds__(256)
__global__ void gather2(const __half* __restrict__ xw16, const ull* __restrict__ csr2,
                        const int* __restrict__ startv, const int* __restrict__ lenv,
                        const float* __restrict__ dinv, const int* __restrict__ gcnt,
                        const int* __restrict__ flags, const int* __restrict__ ovf_b,
                        const ull* __restrict__ ovf_e,
                        const float* __restrict__ convb, float* __restrict__ agg,
                        float* __restrict__ bnacc) {
    __shared__ float red[4][4][32];
    int t = threadIdx.x, lane = t & 63, w = t >> 6;
    int half = lane >> 5, fl = lane & 31, f0 = fl * 2;
    float cb0 = convb[f0], cb1 = convb[f0 + 1];
    float s0s = 0.f, s1s = 0.f, q0s = 0.f, q1s = 0.f;
    int ovfn = flags[1];
    for (int v = blockIdx.x * 4 + w; v < N_NODES; v += 8192) {
        float dv = dinv[v];
        int sb = startv[v], ln = lenv[v];
        float a0 = 0.f, a1 = 0.f, b0 = 0.f, b1 = 0.f;
        if (half == 0) {
            float2 xv = __half22float2(*(const __half2*)(xw16 + (size_t)v * 64 + f0));
            float w2 = dv * dv;
            a0 = w2 * xv.x; a1 = w2 * xv.y;
        }
        int j = 0;
        for (; j + 8 <= ln; j += 8) {
            ull p0 = csr2[sb + j + half];
            ull p1 = csr2[sb + j + 2 + half];
            ull p2 = csr2[sb + j + 4 + half];
            ull p3 = csr2[sb + j + 6 + half];
            float2 x0 = __half22float2(*(const __half2*)(xw16 + (size_t)(uint)p0 * 64 + f0));
            float2 x1 = __half22float2(*(const __half2*)(xw16 + (size_t)(uint)p1 * 64 + f0));
            float2 x2 = __half22float2(*(const __half2*)(xw16 + (size_t)(uint)p2 * 64 + f0));
            float2 x3 = __half22float2(*(const __half2*)(xw16 + (size_t)(uint)p3 * 64 + f0));
            float n0 = __uint_as_float((uint)(p0 >> 32)) * dv;
            float n1 = __uint_as_float((uint)(p1 >> 32)) * dv;
            float n2 = __uint_as_float((uint)(p2 >> 32)) * dv;
            float n3 = __uint_as_float((uint)(p3 >> 32)) * dv;
            a0 = fmaf(n0, x0.x, a0); a1 = fmaf(n0, x0.y, a1);
            b0 = fmaf(n1, x1.x, b0); b1 = fmaf(n1, x1.y, b1);
            a0 = fmaf(n2, x2.x, a0); a1 = fmaf(n2, x2.y, a1);
            b0 = fmaf(n3, x3.x, b0); b1 = fmaf(n3, x3.y, b1);
        }
        for (; j < ln; j += 2) {
            int idx = j + half;
            ull pk = (idx < ln) ? csr2[sb + idx] : 0ull;
            float2 xv = __half22float2(*(const __half2*)(xw16 + (size_t)(uint)pk * 64 + f0));
            float nr = __uint_as_float((uint)(pk >> 32)) * dv;
            a0 = fmaf(nr, xv.x, a0); a1 = fmaf(nr, xv.y, a1);
        }
        float v0 = a0 + b0, v1 = a1 + b1;
        v0 += __shfl_xor(v0, 32, 64);
        v1 += __shfl_xor(v1, 32, 64);
        if (ovfn > 0 && gcnt[v >> 8] > BCAP && half == 0) {   // practically never
            int oc = ovfn; if (oc > OVF_CAP) oc = OVF_CAP;
            int ld = v & 255, b = v >> 8;
            for (int q = 0; q < oc; ++q) {
                if (ovf_b[q] != b) continue;
                ull e = ovf_e[q];
                if ((int)(e >> 56) != ld) continue;
                uint s = (uint)((e >> 18) & 0x1FFFFull);
                float nr = (float)(uint)(e & 0x3FFFFull) * A18_INV * dinv[s] * dv;
                float2 xv = __half22float2(*(const __half2*)(xw16 + (size_t)s * 64 + f0));
                v0 = fmaf(nr, xv.x, v0); v1 = fmaf(nr, xv.y, v1);
            }
        }
        if (half == 0) {
            v0 += cb0; v1 += cb1;
            *(float2*)(agg + (size_t)v * 64 + f0) = make_float2(v0, v1);
            s0s += v0; q0s += v0 * v0; s1s += v1; q1s += v1 * v1;
        }
    }
    if (half == 0) {
        red[0][w][fl] = s0s; red[1][w][fl] = s1s;
        red[2][w][fl] = q0s; red[3][w][fl] = q1s;
    }
    __syncthreads();
    if (t < 32) {
        float s0 = red[0][0][t] + red[0][1][t] + red[0][2][t] + red[0][3][t];
        float s1 = red[1][0][t] + red[1][1][t] + red[1][2][t] + red[1][3][t];
        float q0 = red[2][0][t] + red[2][1][t] + red[2][2][t] + red[2][3][t];
        float q1 = red[3][0][t] + red[3][1][t] + red[3][2][t] + red[3][3][t];
        atomicAdd(&bnacc[2 * t], s0);
        atomicAdd(&bnacc[2 * t + 1], s1);
        atomicAdd(&bnacc[64 + 2 * t], q0);
        atomicAdd(&bnacc[64 + 2 * t + 1], q1);
    }
}

// ---------------- final BN apply: out[:, 64:128]
__launch_bounds__(256)
__global__ void bn_final(const float* __restrict__ agg, const float* __restrict__ bnacc,
                         const float* __restrict__ gamma, const float* __restrict__ beta,
                         float* __restrict__ out) {
    int idx = blockIdx.x * 256 + threadIdx.x;
    int c = idx & 63, v = idx >> 6;
    const float invN = 1.0f / (float)N_NODES;
    float mean = bnacc[c] * invN;
    float var = bnacc[64 + c] * invN - mean * mean;
    float scl = gamma[c] * rsqrtf(var + BN_EPS);
    float bs = beta[c] - mean * scl;
    out[(size_t)v * 128 + 64 + c] = fmaf(agg[idx], scl, bs);
}

extern "C" void kernel_launch(void* const* d_in, const int* in_sizes, int n_in,
                              void* d_out, int out_size, void* d_ws, size_t ws_size,
                              hipStream_t stream) {
    const float* x      = (const float*)d_in[0];
    const int*   eidx   = (const int*)d_in[1];
    const float* attr   = (const float*)d_in[2];
    const float* lin_W  = (const float*)d_in[3];
    const float* lin_b  = (const float*)d_in[4];
    const float* eenc_w = (const float*)d_in[5];
    const float* eenc_b = (const float*)d_in[6];
    const float* conv_W = (const float*)d_in[7];
    const float* conv_b = (const float*)d_in[8];
    const float* gamma  = (const float*)d_in[9];
    const float* beta   = (const float*)d_in[10];
    float* out = (float*)d_out;

    const int* src = eidx;
    const int* dst = eidx + N_EDGES;

    // workspace carve (~70 MB)
    char* p = (char*)d_ws;
    ull* bucket = (ull*)p;   p += (size_t)NBINS * BCAP * 8;    // 14.4 MB
    ull* csr2   = (ull*)p;   p += (size_t)NBINS * BCAP * 8;    // 14.4 MB
    ull* ovf_e  = (ull*)p;   p += (size_t)OVF_CAP * 8;
    float* h0   = (float*)p; p += (size_t)N_NODES * 64 * 4;    // 25.6 MB (aliased: agg)
    __half* xw16 = (__half*)p; p += (size_t)N_NODES * 64 * 2;  // 12.8 MB
    float* dinv = (float*)p; p += (size_t)N_NODES * 4;
    float* wa   = (float*)p; p += (size_t)N_NODES * 4;
    int* win    = (int*)p;   p += (size_t)N_NODES * 4;
    int* startv = (int*)p;   p += (size_t)N_NODES * 4;
    int* lenv   = (int*)p;   p += (size_t)N_NODES * 4;
    int* ovf_b  = (int*)p;   p += (size_t)OVF_CAP * 4;
    int* gcnt   = (int*)p;   p += (NBINS + 1) * 4 + 20;
    uint* zbitmap = (uint*)p; p += 3125 * 4 + 12;
    int* flags  = (int*)p;   p += 64;
    float* bnacc = (float*)p; p += 256 * 4;                    // [2][128]
    float* agg = h0;   // h0 dead after gemm_l0

    init_kernel<<<NBLK_N, 256, 0, stream>>>(gcnt, win, zbitmap, flags, bnacc);
    partition_gemm<<<NPART + NBLK_G, 256, 0, stream>>>(src, dst, attr, bucket, gcnt,
                                                       flags, ovf_b, ovf_e,
                                                       x, lin_W, lin_b, h0);
    finalize_reorder<<<NBINS, 256, 0, stream>>>(bucket, gcnt, ovf_b, ovf_e,
                                                flags, zbitmap, dinv, wa,
                                                csr2, startv, lenv);
    fixup_scan<<<NBLK_E, 256, 0, stream>>>(src, flags, zbitmap, win);
    fixup_apply<<<NBLK_N, 256, 0, stream>>>(flags, zbitmap, win, attr, wa);

    gemm_l0_nrm<<<NBINS + NBLK_G, 256, 0, stream>>>(h0, conv_W, wa, eenc_w, eenc_b,
                                                    xw16, csr2, gcnt, dinv);
    gather2<<<2048, 256, 0, stream>>>(xw16, csr2, startv, lenv, dinv, gcnt,
                                      flags, ovf_b, ovf_e, conv_b, agg, bnacc);
    gemm_l1<<<NBLK_G, 256, 0, stream>>>(agg, bnacc, gamma, beta,
                                        conv_W + 64 * 64, out, xw16);
    gather2<<<2048, 256, 0, stream>>>(xw16, csr2, startv, lenv, dinv, gcnt,
                                      flags, ovf_b, ovf_e, conv_b + 64, agg, bnacc + 128);
    bn_final<<<25000, 256, 0, stream>>>(agg, bnacc + 128, gamma + 64, beta + 64, out);
}

// Round 7
// 439.332 us; speedup vs baseline: 1.3223x; 1.3223x over previous
//
#include <hip/hip_runtime.h>
#include <hip/hip_fp16.h>

#define N_NODES 100000
#define N_EDGES 1600000
#define BN_EPS 1e-5f
#define NBLK_E 6250      /* N_EDGES / 256 exact */
#define NBLK_G 3125      /* N_NODES / 32 exact */
#define NBLK_N 391       /* ceil(N_NODES/256) */
#define NBINS 391        /* buckets of 256 nodes */
#define BCAP 4608        /* entries per bucket (lambda=4096, +8 sigma) */
#define PT 4096          /* partition tile (edges per block) */
#define NPART 391        /* ceil(N_EDGES/PT) */
#define OVF_CAP 32768
#define A18 262144.0f
#define A18_INV 3.814697265625e-6f   /* 2^-18 */
typedef unsigned long long ull;
typedef unsigned int uint;

// bucket entry = local_d(8) | edge_idx(21) | src(17) | attr_q18(18)
// csr2 entry (after finalize) = attr_q18(high32) | src(low32)
// csr2 entry (after nrm blocks of gemm_l0_nrm) = f32(attr*dinv[src]) | src

// ---------------- init
__global__ void init_kernel(int* gcnt, int* win, uint* zbitmap, int* flags, float* bnacc) {
    int v = blockIdx.x * blockDim.x + threadIdx.x;
    if (v < N_NODES) win[v] = -1;
    if (v < NBINS) gcnt[v] = 0;
    if (v < 3125) zbitmap[v] = 0;
    if (v < 2) flags[v] = 0;          // [0]=zero-indeg-any  [1]=ovf_cnt
    if (v < 256) bnacc[v] = 0.0f;     // [2 layers][sum64|sq64]
}

// ---------------- partition (LDS-staged counting sort into 391 buckets) + fused h0 GEMM
__launch_bounds__(256)
__global__ void partition_gemm(const int* __restrict__ src, const int* __restrict__ dst,
                               const float* __restrict__ attr,
                               ull* __restrict__ bucket, int* __restrict__ gcnt,
                               int* __restrict__ flags, int* __restrict__ ovf_b,
                               ull* __restrict__ ovf_e,
                               const float* __restrict__ x, const float* __restrict__ lin_W,
                               const float* __restrict__ lin_b, float* __restrict__ h0) {
    __shared__ ull ent[PT];               // 32 KB
    __shared__ unsigned short ebin[PT];   // 8 KB
    __shared__ int hist[NBINS];
    __shared__ int cur[NBINS];
    __shared__ int gdel[NBINS];
    __shared__ int sc[512];
    int t = threadIdx.x;
    if (blockIdx.x < NPART) {
        int e0 = blockIdx.x * PT;
        int n = N_EDGES - e0; if (n > PT) n = PT;
        for (int b = t; b < NBINS; b += 256) hist[b] = 0;
        __syncthreads();
        for (int k = t; k < n; k += 256) atomicAdd(&hist[dst[e0 + k] >> 8], 1);
        __syncthreads();
        sc[t] = (t < NBINS) ? hist[t] : 0;
        sc[t + 256] = (t + 256 < NBINS) ? hist[t + 256] : 0;
        __syncthreads();
        for (int off = 1; off < 512; off <<= 1) {
            int a0 = sc[t] + ((t >= off) ? sc[t - off] : 0);
            int a1 = sc[t + 256] + sc[t + 256 - off];
            __syncthreads();
            sc[t] = a0; sc[t + 256] = a1;
            __syncthreads();
        }
        for (int b = t; b < NBINS; b += 256) {
            int lb = sc[b] - hist[b];
            cur[b] = lb;
            int gb = atomicAdd(&gcnt[b], hist[b]);
            gdel[b] = gb - lb;
        }
        __syncthreads();
        for (int k = t; k < n; k += 256) {
            int i = e0 + k;
            int d = dst[i];
            uint aq = (uint)(attr[i] * A18); if (aq > 0x3FFFFu) aq = 0x3FFFFu;
            int bin = d >> 8;
            ull e = ((ull)(d & 255) << 56) | ((ull)i << 35) | ((ull)src[i] << 18) | aq;
            int p = atomicAdd(&cur[bin], 1);
            ent[p] = e;
            ebin[p] = (unsigned short)bin;
        }
        __syncthreads();
        for (int k = t; k < n; k += 256) {
            int b = ebin[k];
            int off = k + gdel[b];
            if (off < BCAP) bucket[(size_t)b * BCAP + off] = ent[k];
            else {
                int q = atomicAdd(&flags[1], 1);
                if (q < OVF_CAP) { ovf_b[q] = b; ovf_e[q] = ent[k]; }
            }
        }
        return;
    }
    // ---- fused GEMM blocks: h0 = x @ lin_W + lin_b
    float* xs = (float*)ent;
    int lane = t & 63, w = t >> 6;
    int base = (blockIdx.x - NPART) * 32;
    const float4* Xv = (const float4*)(x + (size_t)base * 64);
    float4* xsv = (float4*)xs;
    xsv[t] = Xv[t];
    xsv[t + 256] = Xv[t + 256];
    float wc[64];
    #pragma unroll
    for (int k = 0; k < 64; ++k) wc[k] = lin_W[k * 64 + lane];
    __syncthreads();
    float bval = lin_b[lane];
    for (int rr = 0; rr < 8; ++rr) {
        int rl = w * 8 + rr;
        float acc = bval;
        #pragma unroll
        for (int k = 0; k < 64; ++k) acc = fmaf(xs[rl * 64 + k], wc[k], acc);
        h0[(size_t)(base + rl) * 64 + lane] = acc;
    }
}

// ---------------- finalize+reorder: node-sort entries -> csr2 (coalesced),
// per-node start/len, deg->dinv, last-write-winner attr, zero-indeg marks.
__launch_bounds__(256)
__global__ void finalize_reorder(const ull* __restrict__ bucket, const int* __restrict__ gcnt,
                                 const int* __restrict__ ovf_b, const ull* __restrict__ ovf_e,
                                 int* __restrict__ flags, uint* __restrict__ zbitmap,
                                 float* __restrict__ dinv, float* __restrict__ wa,
                                 ull* __restrict__ csr2, int* __restrict__ startv,
                                 int* __restrict__ lenv) {
    __shared__ ull ent[BCAP];        // 36.8 KB
    __shared__ int cnt[256];
    __shared__ int sc[256];
    __shared__ int cur[256];
    __shared__ int cbase[257];
    int t = threadIdx.x, b = blockIdx.x;
    int len = gcnt[b], blen = len < BCAP ? len : BCAP;
    const ull* bb = bucket + (size_t)b * BCAP;
    cnt[t] = 0;
    __syncthreads();
    ull r[18];
    #pragma unroll
    for (int k = 0; k < 18; ++k) {
        int j = k * 256 + t;
        r[k] = 0;
        if (j < blen) {
            ull e = bb[j];
            r[k] = e;
            atomicAdd(&cnt[(int)(e >> 56)], 1);
        }
    }
    __syncthreads();
    sc[t] = cnt[t];
    __syncthreads();
    for (int off = 1; off < 256; off <<= 1) {
        int a = sc[t] + ((t >= off) ? sc[t - off] : 0);
        __syncthreads();
        sc[t] = a;
        __syncthreads();
    }
    cbase[t + 1] = sc[t];
    if (t == 0) cbase[0] = 0;
    cur[t] = sc[t] - cnt[t];
    __syncthreads();
    #pragma unroll
    for (int k = 0; k < 18; ++k) {
        int j = k * 256 + t;
        if (j < blen) {
            ull e = r[k];
            int p = atomicAdd(&cur[(int)(e >> 56)], 1);
            ent[p] = e;
        }
    }
    __syncthreads();
    size_t base = (size_t)b * BCAP;
    for (int k = t; k < blen; k += 256) {
        ull e = ent[k];
        csr2[base + k] = (((ull)(e & 0x3FFFFull)) << 32) | ((e >> 18) & 0x1FFFFull);
    }
    int j0 = cbase[t], j1 = cbase[t + 1];
    float sum = 0.0f; uint winx = 0, wat = 0;
    for (int j = j0; j < j1; ++j) {
        ull e = ent[j];
        uint aq = (uint)(e & 0x3FFFFull);
        sum += (float)aq * A18_INV;
        uint ei = (uint)((e >> 35) & 0x1FFFFFull) + 1u;
        if (ei > winx) { winx = ei; wat = aq; }
    }
    if (len > BCAP) {                      // overflow (practically never)
        int oc = flags[1]; if (oc > OVF_CAP) oc = OVF_CAP;
        for (int q = 0; q < oc; ++q) {
            if (ovf_b[q] != b) continue;
            ull e = ovf_e[q];
            if ((int)(e >> 56) != t) continue;
            uint aq = (uint)(e & 0x3FFFFull);
            sum += (float)aq * A18_INV;
            uint ei = (uint)((e >> 35) & 0x1FFFFFull) + 1u;
            if (ei > winx) { winx = ei; wat = aq; }
        }
    }
    int v = b * 256 + t;
    if (v < N_NODES) {
        dinv[v] = rsqrtf(1.0f + sum);
        startv[v] = (int)(base + j0);
        lenv[v] = j1 - j0;
        if (winx > 0) {
            wa[v] = (float)wat * A18_INV;
        } else {
            wa[v] = -1.0f;
            atomicOr(&zbitmap[v >> 5], 1u << (v & 31));
            flags[0] = 1;
        }
    }
}

// ---------------- fixup: src-side winner for zero-in-degree nodes (early-exit)
__global__ void fixup_scan(const int* __restrict__ src, const int* __restrict__ flags,
                           const uint* __restrict__ zbitmap, int* __restrict__ win) {
    if (flags[0] == 0) return;
    int i = blockIdx.x * 256 + threadIdx.x;
    int s = src[i];
    if ((zbitmap[s >> 5] >> (s & 31)) & 1u) atomicMax(&win[s], i);
}

__global__ void fixup_apply(const int* __restrict__ flags, const uint* __restrict__ zbitmap,
                            const int* __restrict__ win, const float* __restrict__ attr,
                            float* __restrict__ wa) {
    if (flags[0] == 0) return;
    int v = blockIdx.x * 256 + threadIdx.x;
    if (v >= N_NODES) return;
    if (((zbitmap[v >> 5] >> (v & 31)) & 1u) && win[v] >= 0) wa[v] = attr[win[v]];
}

// ---------------- layer-0 GEMM + fused nrm-precompute blocks
// nrm blocks: csr2 entry (aq<<32|src) -> (f32(aq*dinv[src])<<32|src)
__launch_bounds__(256)
__global__ void gemm_l0_nrm(const float* __restrict__ h0, const float* __restrict__ W,
                            const float* __restrict__ wa, const float* __restrict__ ew,
                            const float* __restrict__ eb, __half* __restrict__ xw16,
                            ull* __restrict__ csr2, const int* __restrict__ gcnt,
                            const float* __restrict__ dinv) {
    __shared__ float xs[2048];
    int t = threadIdx.x;
    if (blockIdx.x < NBINS) {
        int b = blockIdx.x;
        int len = gcnt[b], blen = len < BCAP ? len : BCAP;
        ull* c = csr2 + (size_t)b * BCAP;
        for (int k = t; k < blen; k += 256) {
            ull pk = c[k];
            uint s = (uint)pk;
            float np = (float)(uint)(pk >> 32) * A18_INV * dinv[s];
            c[k] = ((ull)__float_as_uint(np) << 32) | s;
        }
        return;
    }
    int lane = t & 63, w = t >> 6;
    int base = (blockIdx.x - NBINS) * 32;
    const float4* Hv = (const float4*)(h0 + (size_t)base * 64);
    #pragma unroll
    for (int q = 0; q < 2; ++q) {
        int idx = t + q * 256;
        int rl = idx >> 4, f0 = (idx & 15) * 4;
        float4 v = Hv[idx];
        float wav = wa[base + rl];
        if (wav >= 0.0f) {
            v.x = fmaxf(fmaf(wav, ew[f0 + 0], v.x + eb[f0 + 0]), 0.0f);
            v.y = fmaxf(fmaf(wav, ew[f0 + 1], v.y + eb[f0 + 1]), 0.0f);
            v.z = fmaxf(fmaf(wav, ew[f0 + 2], v.z + eb[f0 + 2]), 0.0f);
            v.w = fmaxf(fmaf(wav, ew[f0 + 3], v.w + eb[f0 + 3]), 0.0f);
        }
        ((float4*)xs)[idx] = v;
    }
    float wc[64];
    #pragma unroll
    for (int k = 0; k < 64; ++k) wc[k] = W[k * 64 + lane];
    __syncthreads();
    for (int rr = 0; rr < 8; ++rr) {
        int rl = w * 8 + rr;
        float acc = 0.0f;
        #pragma unroll
        for (int k = 0; k < 64; ++k) acc = fmaf(xs[rl * 64 + k], wc[k], acc);
        xw16[(size_t)(base + rl) * 64 + lane] = __float2half(acc);
    }
}

// ---------------- layer-1 GEMM: stage agg0 + BN0 + relu, write out[:,0:64], fp16 xw
__launch_bounds__(256)
__global__ void gemm_l1(const float* __restrict__ agg, const float* __restrict__ bnacc,
                        const float* __restrict__ gamma, const float* __restrict__ beta,
                        const float* __restrict__ W, float* __restrict__ out,
                        __half* __restrict__ xw16) {
    __shared__ float xs[2048];
    int t = threadIdx.x, lane = t & 63, w = t >> 6;
    int base = blockIdx.x * 32;
    const float4* Av = (const float4*)(agg + (size_t)base * 64);
    const float invN = 1.0f / (float)N_NODES;
    #pragma unroll
    for (int q = 0; q < 2; ++q) {
        int idx = t + q * 256;
        int rl = idx >> 4, f0 = (idx & 15) * 4;
        float4 v = Av[idx];
        float vv[4] = {v.x, v.y, v.z, v.w};
        #pragma unroll
        for (int c = 0; c < 4; ++c) {
            int f = f0 + c;
            float mean = bnacc[f] * invN;
            float var = bnacc[64 + f] * invN - mean * mean;
            float scl = gamma[f] * rsqrtf(var + BN_EPS);
            float bs = beta[f] - mean * scl;
            vv[c] = fmaxf(fmaf(vv[c], scl, bs), 0.0f);
        }
        float4 r = {vv[0], vv[1], vv[2], vv[3]};
        ((float4*)xs)[idx] = r;
        *(float4*)(out + (size_t)(base + rl) * 128 + f0) = r;   // out[:, 0:64]
    }
    float wc[64];
    #pragma unroll
    for (int k = 0; k < 64; ++k) wc[k] = W[k * 64 + lane];
    __syncthreads();
    for (int rr = 0; rr < 8; ++rr) {
        int rl = w * 8 + rr;
        float acc = 0.0f;
        #pragma unroll
        for (int k = 0; k < 64; ++k) acc = fmaf(xs[rl * 64 + k], wc[k], acc);
        xw16[(size_t)(base + rl) * 64 + lane] = __float2half(acc);
    }
}

// ---------------- gather v3: 4 nodes per wave; lane=(ng:2|fl:4); 8B/lane row loads;
// entry chunks of 16/node coalesced (all 64 lanes), addresses register-fed via shfl
__launch_bounds__(256)
__global__ void gather4(const __half* __restrict__ xw16, const ull* __restrict__ csr2,
                        const int* __restrict__ startv, const int* __restrict__ lenv,
                        const float* __restrict__ dinv, const int* __restrict__ gcnt,
                        const int* __restrict__ flags, const int* __restrict__ ovf_b,
                        const ull* __restrict__ ovf_e,
                        const float* __restrict__ convb, float* __restrict__ agg,
                        float* __restrict__ bnacc) {
    __shared__ float reds[4][64];
    __shared__ float redq[4][64];
    int t = threadIdx.x, lane = t & 63, w = t >> 6;
    int ng = lane >> 4, fl = lane & 15, f0 = fl * 4, ngb = ng << 4;
    float cb0 = convb[f0], cb1 = convb[f0 + 1], cb2 = convb[f0 + 2], cb3 = convb[f0 + 3];
    float s0 = 0.f, s1 = 0.f, s2 = 0.f, s3 = 0.f;
    float q0 = 0.f, q1 = 0.f, q2 = 0.f, q3 = 0.f;
    int ovfn = flags[1];
    for (int v = blockIdx.x * 16 + w * 4 + ng; v < N_NODES; v += 32768) {
        float dv = dinv[v];
        int sb = startv[v], ln = lenv[v];
        float2 raw = *(const float2*)(xw16 + (size_t)v * 64 + f0);
        float2 xv01 = __half22float2(*(__half2*)&raw.x);
        float2 xv23 = __half22float2(*(__half2*)&raw.y);
        float w2 = dv * dv;
        float a0 = w2 * xv01.x, a1 = w2 * xv01.y, a2 = w2 * xv23.x, a3 = w2 * xv23.y;
        float b0 = 0.f, b1 = 0.f, b2 = 0.f, b3 = 0.f;
        for (int c0 = 0; c0 < ln; c0 += 16) {
            int m = ln - c0; if (m > 16) m = 16;
            ull pk = (fl < m) ? csr2[sb + c0 + fl] : 0ull;
            int j = 0;
            for (; j + 4 <= m; j += 4) {
                ull pA = __shfl(pk, ngb + j, 64);
                ull pB = __shfl(pk, ngb + j + 1, 64);
                ull pC = __shfl(pk, ngb + j + 2, 64);
                ull pD = __shfl(pk, ngb + j + 3, 64);
                float2 rA = *(const float2*)(xw16 + (size_t)(uint)pA * 64 + f0);
                float2 rB = *(const float2*)(xw16 + (size_t)(uint)pB * 64 + f0);
                float2 rC = *(const float2*)(xw16 + (size_t)(uint)pC * 64 + f0);
                float2 rD = *(const float2*)(xw16 + (size_t)(uint)pD * 64 + f0);
                float nA = __uint_as_float((uint)(pA >> 32)) * dv;
                float nB = __uint_as_float((uint)(pB >> 32)) * dv;
                float nC = __uint_as_float((uint)(pC >> 32)) * dv;
                float nD = __uint_as_float((uint)(pD >> 32)) * dv;
                float2 xA01 = __half22float2(*(__half2*)&rA.x);
                float2 xA23 = __half22float2(*(__half2*)&rA.y);
                float2 xB01 = __half22float2(*(__half2*)&rB.x);
                float2 xB23 = __half22float2(*(__half2*)&rB.y);
                float2 xC01 = __half22float2(*(__half2*)&rC.x);
                float2 xC23 = __half22float2(*(__half2*)&rC.y);
                float2 xD01 = __half22float2(*(__half2*)&rD.x);
                float2 xD23 = __half22float2(*(__half2*)&rD.y);
                a0 = fmaf(nA, xA01.x, a0); a1 = fmaf(nA, xA01.y, a1);
                a2 = fmaf(nA, xA23.x, a2); a3 = fmaf(nA, xA23.y, a3);
                b0 = fmaf(nB, xB01.x, b0); b1 = fmaf(nB, xB01.y, b1);
                b2 = fmaf(nB, xB23.x, b2); b3 = fmaf(nB, xB23.y, b3);
                a0 = fmaf(nC, xC01.x, a0); a1 = fmaf(nC, xC01.y, a1);
                a2 = fmaf(nC, xC23.x, a2); a3 = fmaf(nC, xC23.y, a3);
                b0 = fmaf(nD, xD01.x, b0); b1 = fmaf(nD, xD01.y, b1);
                b2 = fmaf(nD, xD23.x, b2); b3 = fmaf(nD, xD23.y, b3);
            }
            for (; j < m; ++j) {
                ull pA = __shfl(pk, ngb + j, 64);
                float2 rA = *(const float2*)(xw16 + (size_t)(uint)pA * 64 + f0);
                float nA = __uint_as_float((uint)(pA >> 32)) * dv;
                float2 xA01 = __half22float2(*(__half2*)&rA.x);
                float2 xA23 = __half22float2(*(__half2*)&rA.y);
                a0 = fmaf(nA, xA01.x, a0); a1 = fmaf(nA, xA01.y, a1);
                a2 = fmaf(nA, xA23.x, a2); a3 = fmaf(nA, xA23.y, a3);
            }
        }
        float t0 = a0 + b0, t1 = a1 + b1, t2 = a2 + b2, t3 = a3 + b3;
        if (ovfn > 0 && gcnt[v >> 8] > BCAP) {     // practically never
            int oc = ovfn; if (oc > OVF_CAP) oc = OVF_CAP;
            int ld = v & 255, b = v >> 8;
            for (int q = 0; q < oc; ++q) {
                if (ovf_b[q] != b) continue;
                ull e = ovf_e[q];
                if ((int)(e >> 56) != ld) continue;
                uint s = (uint)((e >> 18) & 0x1FFFFull);
                float nr = (float)(uint)(e & 0x3FFFFull) * A18_INV * dinv[s] * dv;
                float2 rr = *(const float2*)(xw16 + (size_t)s * 64 + f0);
                float2 x01 = __half22float2(*(__half2*)&rr.x);
                float2 x23 = __half22float2(*(__half2*)&rr.y);
                t0 = fmaf(nr, x01.x, t0); t1 = fmaf(nr, x01.y, t1);
                t2 = fmaf(nr, x23.x, t2); t3 = fmaf(nr, x23.y, t3);
            }
        }
        t0 += cb0; t1 += cb1; t2 += cb2; t3 += cb3;
        *(float4*)(agg + (size_t)v * 64 + f0) = make_float4(t0, t1, t2, t3);
        s0 += t0; q0 += t0 * t0;
        s1 += t1; q1 += t1 * t1;
        s2 += t2; q2 += t2 * t2;
        s3 += t3; q3 += t3 * t3;
    }
    // reduce across the 4 node-groups (lanes fl, 16+fl, 32+fl, 48+fl)
    s0 += __shfl_xor(s0, 16, 64); s0 += __shfl_xor(s0, 32, 64);
    s1 += __shfl_xor(s1, 16, 64); s1 += __shfl_xor(s1, 32, 64);
    s2 += __shfl_xor(s2, 16, 64); s2 += __shfl_xor(s2, 32, 64);
    s3 += __shfl_xor(s3, 16, 64); s3 += __shfl_xor(s3, 32, 64);
    q0 += __shfl_xor(q0, 16, 64); q0 += __shfl_xor(q0, 32, 64);
    q1 += __shfl_xor(q1, 16, 64); q1 += __shfl_xor(q1, 32, 64);
    q2 += __shfl_xor(q2, 16, 64); q2 += __shfl_xor(q2, 32, 64);
    q3 += __shfl_xor(q3, 16, 64); q3 += __shfl_xor(q3, 32, 64);
    if (ng == 0) {
        reds[w][f0] = s0; reds[w][f0 + 1] = s1; reds[w][f0 + 2] = s2; reds[w][f0 + 3] = s3;
        redq[w][f0] = q0; redq[w][f0 + 1] = q1; redq[w][f0 + 2] = q2; redq[w][f0 + 3] = q3;
    }
    __syncthreads();
    if (t < 64) {
        float ss = reds[0][t] + reds[1][t] + reds[2][t] + reds[3][t];
        float qq = redq[0][t] + redq[1][t] + redq[2][t] + redq[3][t];
        atomicAdd(&bnacc[t], ss);
        atomicAdd(&bnacc[64 + t], qq);
    }
}

// ---------------- final BN apply: out[:, 64:128]
__launch_bounds__(256)
__global__ void bn_final(const float* __restrict__ agg, const float* __restrict__ bnacc,
                         const float* __restrict__ gamma, const float* __restrict__ beta,
                         float* __restrict__ out) {
    int idx = blockIdx.x * 256 + threadIdx.x;
    int c = idx & 63, v = idx >> 6;
    const float invN = 1.0f / (float)N_NODES;
    float mean = bnacc[c] * invN;
    float var = bnacc[64 + c] * invN - mean * mean;
    float scl = gamma[c] * rsqrtf(var + BN_EPS);
    float bs = beta[c] - mean * scl;
    out[(size_t)v * 128 + 64 + c] = fmaf(agg[idx], scl, bs);
}

extern "C" void kernel_launch(void* const* d_in, const int* in_sizes, int n_in,
                              void* d_out, int out_size, void* d_ws, size_t ws_size,
                              hipStream_t stream) {
    const float* x      = (const float*)d_in[0];
    const int*   eidx   = (const int*)d_in[1];
    const float* attr   = (const float*)d_in[2];
    const float* lin_W  = (const float*)d_in[3];
    const float* lin_b  = (const float*)d_in[4];
    const float* eenc_w = (const float*)d_in[5];
    const float* eenc_b = (const float*)d_in[6];
    const float* conv_W = (const float*)d_in[7];
    const float* conv_b = (const float*)d_in[8];
    const float* gamma  = (const float*)d_in[9];
    const float* beta   = (const float*)d_in[10];
    float* out = (float*)d_out;

    const int* src = eidx;
    const int* dst = eidx + N_EDGES;

    // workspace carve (~70 MB)
    char* p = (char*)d_ws;
    ull* bucket = (ull*)p;   p += (size_t)NBINS * BCAP * 8;    // 14.4 MB
    ull* csr2   = (ull*)p;   p += (size_t)NBINS * BCAP * 8;    // 14.4 MB
    ull* ovf_e  = (ull*)p;   p += (size_t)OVF_CAP * 8;
    float* h0   = (float*)p; p += (size_t)N_NODES * 64 * 4;    // 25.6 MB (aliased: agg)
    __half* xw16 = (__half*)p; p += (size_t)N_NODES * 64 * 2;  // 12.8 MB
    float* dinv = (float*)p; p += (size_t)N_NODES * 4;
    float* wa   = (float*)p; p += (size_t)N_NODES * 4;
    int* win    = (int*)p;   p += (size_t)N_NODES * 4;
    int* startv = (int*)p;   p += (size_t)N_NODES * 4;
    int* lenv   = (int*)p;   p += (size_t)N_NODES * 4;
    int* ovf_b  = (int*)p;   p += (size_t)OVF_CAP * 4;
    int* gcnt   = (int*)p;   p += (NBINS + 1) * 4 + 20;
    uint* zbitmap = (uint*)p; p += 3125 * 4 + 12;
    int* flags  = (int*)p;   p += 64;
    float* bnacc = (float*)p; p += 256 * 4;                    // [2][128]
    float* agg = h0;   // h0 dead after gemm_l0_nrm

    init_kernel<<<NBLK_N, 256, 0, stream>>>(gcnt, win, zbitmap, flags, bnacc);
    partition_gemm<<<NPART + NBLK_G, 256, 0, stream>>>(src, dst, attr, bucket, gcnt,
                                                       flags, ovf_b, ovf_e,
                                                       x, lin_W, lin_b, h0);
    finalize_reorder<<<NBINS, 256, 0, stream>>>(bucket, gcnt, ovf_b, ovf_e,
                                                flags, zbitmap, dinv, wa,
                                                csr2, startv, lenv);
    fixup_scan<<<NBLK_E, 256, 0, stream>>>(src, flags, zbitmap, win);
    fixup_apply<<<NBLK_N, 256, 0, stream>>>(flags, zbitmap, win, attr, wa);

    gemm_l0_nrm<<<NBINS + NBLK_G, 256, 0, stream>>>(h0, conv_W, wa, eenc_w, eenc_b,
                                                    xw16, csr2, gcnt, dinv);
    gather4<<<2048, 256, 0, stream>>>(xw16, csr2, startv, lenv, dinv, gcnt,
                                      flags, ovf_b, ovf_e, conv_b, agg, bnacc);
    gemm_l1<<<NBLK_G, 256, 0, stream>>>(agg, bnacc, gamma, beta,
                                        conv_W + 64 * 64, out, xw16);
    gather4<<<2048, 256, 0, stream>>>(xw16, csr2, startv, lenv, dinv, gcnt,
                                      flags, ovf_b, ovf_e, conv_b + 64, agg, bnacc + 128);
    bn_final<<<25000, 256, 0, stream>>>(agg, bnacc + 128, gamma + 64, beta + 64, out);
}